// Round 9
// baseline (182.067 us; speedup 1.0000x reference)
//
#include <hip/hip_runtime.h>
#include <math.h>

#define Bn 32
#define Cn 64
#define Ln 2048
#define NFREQ 1025
#define S0c 341
#define S1c 341
#define S2c 343

#define PI_D 3.14159265358979323846

typedef double v4d __attribute__((ext_vector_type(4)));

// padded LDS index: breaks power-of-2 stride bank conflicts
#define PADIX(i) ((i) + ((i) >> 4))

// ---------------- K1: prep — twiddle table + zero Y (for split-K atomics) ----------------
__global__ __launch_bounds__(256) void k_prep(double2* __restrict__ tw,
                                              double* __restrict__ Y) {
    int tid = threadIdx.x;
    int gid = blockIdx.x * 256 + tid;
    if (blockIdx.x < 8) {
        int t = gid;
        double ang = -2.0 * PI_D * (double)t / 2048.0;
        double s, c;
        sincos(ang, &s, &c);
        tw[t] = make_double2(c, s);
    }
    const int NY = 2048 * NFREQ;
    for (int i = gid; i < NY; i += 2048 * 256) Y[i] = 0.0;
}

// radix-4 digit reversal of a 10-bit index
__device__ __forceinline__ int rev4_10(unsigned x) {
    unsigned t = __brev(x) >> 22;                       // full 10-bit reversal
    return (int)(((t & 0x155u) << 1) | ((t >> 1) & 0x155u));  // un-reverse bit pairs
}

// ---------------- K2: packed-real rfft, 2 rows/block, radix-4 + split ----------------
__global__ __launch_bounds__(256) void k_fft(const float* __restrict__ X,
                                             const double2* __restrict__ tw,
                                             float* __restrict__ XF) {
    __shared__ double re[2][1088];
    __shared__ double im[2][1088];
    int row0 = blockIdx.x * 2;
    int tid = threadIdx.x;
    const float2* xr0 = (const float2*)(X + (size_t)row0 * Ln);
    const float2* xr1 = (const float2*)(X + (size_t)(row0 + 1) * Ln);
    for (int m = tid; m < 1024; m += 256) {
        float2 v0 = xr0[m];
        float2 v1 = xr1[m];
        int p = PADIX(m);
        re[0][p] = (double)v0.x; im[0][p] = (double)v0.y;
        re[1][p] = (double)v1.x; im[1][p] = (double)v1.y;
    }
    __syncthreads();
    // 5 radix-4 DIF stages, one butterfly per thread per row (twiddles shared)
    #pragma unroll
    for (int s = 0; s < 5; ++s) {
        int log2Q = 8 - 2 * s;
        int Q = 1 << log2Q;
        int k = tid & (Q - 1);
        int g = tid >> log2Q;
        int base = (g << (log2Q + 2)) + k;
        int i0 = PADIX(base), i1 = PADIX(base + Q), i2 = PADIX(base + 2 * Q), i3 = PADIX(base + 3 * Q);
        int step = 2 << (2 * s);
        double2 w1 = tw[k * step];
        double2 w2 = tw[2 * k * step];
        double2 w3 = tw[3 * k * step];
        #pragma unroll
        for (int r = 0; r < 2; ++r) {
            double ar = re[r][i0], ai = im[r][i0];
            double br = re[r][i1], bi = im[r][i1];
            double cr = re[r][i2], ci = im[r][i2];
            double dr = re[r][i3], di = im[r][i3];
            double t0r = ar + cr, t0i = ai + ci;
            double t1r = ar - cr, t1i = ai - ci;
            double t2r = br + dr, t2i = bi + di;
            double t3r = br - dr, t3i = bi - di;
            re[r][i0] = t0r + t2r; im[r][i0] = t0i + t2i;
            double u1r = t1r + t3i, u1i = t1i - t3r;
            re[r][i1] = u1r * w1.x - u1i * w1.y; im[r][i1] = u1r * w1.y + u1i * w1.x;
            double u2r = t0r - t2r, u2i = t0i - t2i;
            re[r][i2] = u2r * w2.x - u2i * w2.y; im[r][i2] = u2r * w2.y + u2i * w2.x;
            double u3r = t1r - t3i, u3i = t1i + t3r;
            re[r][i3] = u3r * w3.x - u3i * w3.y; im[r][i3] = u3r * w3.y + u3i * w3.x;
        }
        __syncthreads();
    }
    // split: X[k] = E_k + e^{-2pi i k/2048} O_k (Z positions radix-4-digit-reversed)
    float* out0 = XF + (size_t)row0 * NFREQ;
    float* out1 = XF + (size_t)(row0 + 1) * NFREQ;
    for (int k = tid; k <= 1024; k += 256) {
        int rv, rv2;
        double2 t;
        bool mid = (k != 0) && (k != 1024);
        if (mid) {
            rv  = PADIX(rev4_10((unsigned)k));
            rv2 = PADIX(rev4_10((unsigned)(1024 - k)));
            t = tw[k];
        }
        #pragma unroll
        for (int r = 0; r < 2; ++r) {
            double Xr, Xi;
            if (k == 0)        { Xr = re[r][0] + im[r][0]; Xi = 0.0; }
            else if (k == 1024){ Xr = re[r][0] - im[r][0]; Xi = 0.0; }
            else {
                double Zr = re[r][rv],  Zi = im[r][rv];
                double Wr = re[r][rv2], Wi = im[r][rv2];
                double Er = 0.5 * (Zr + Wr), Ei = 0.5 * (Zi - Wi);
                double Or = 0.5 * (Zi + Wi), Oi = -0.5 * (Zr - Wr);
                Xr = Er + t.x * Or - t.y * Oi;
                Xi = Ei + t.x * Oi + t.y * Or;
            }
            float v = (float)sqrt(Xr * Xr + Xi * Xi);
            if (r == 0) out0[k] = v; else out1[k] = v;
        }
    }
}

// ---------------- K3: fused 3-band split-K GEMM via v_mfma_f64_16x16x4 ----------------
// grid (32 row-tiles, 6 col-tiles, 3 bands x 2 K-halves) = 1152 blocks; block 256 = 4 waves.
// Tile 64x64, row-major f32 LDS stride 34 (conflict-free). Halves combined with f64
// atomic add into zero-initialized Y (2 commutative contributors -> deterministic).
__global__ __launch_bounds__(256) void k_gemm(const float* __restrict__ XF,
                                              const float* __restrict__ A0,
                                              const float* __restrict__ A1,
                                              const float* __restrict__ A2,
                                              double* __restrict__ Y) {
    const int Sarr[3] = {S0c, S1c, S2c};
    const int Oarr[3] = {0, S0c, S0c + S1c};
    int bz = blockIdx.z;
    int z = bz >> 1, half = bz & 1;
    const float* A = (z == 0) ? A0 : ((z == 1) ? A1 : A2);
    int S = Sarr[z], O = Oarr[z];
    const int Sh = 192;                       // K-split point (multiple of 32)
    int k_lo = half ? Sh : 0;
    int k_hi = half ? S : Sh;

    __shared__ float sX[64][34];   // [row][k] stride 34: writes 2-way, reads 2-way (free)
    __shared__ float sA[64][34];   // [col(d)][k]
    int r0 = blockIdx.x * 64;
    int d0 = blockIdx.y * 64;
    int tid = threadIdx.x;
    int lane = tid & 63, w = tid >> 6;
    int wm = (w >> 1) * 32, wn = (w & 1) * 32;   // wave's 32x32 quadrant
    int fm = lane & 15, kq = lane >> 4;          // staged frag coords
    int kl = tid & 31, rl = tid >> 5;            // staging coords

    // ---- runtime layout calibration (proven round 7) ----
    v4d zero = {0.0, 0.0, 0.0, 0.0};
    double aval = (double)fm;
    v4d calR = __builtin_amdgcn_mfma_f64_16x16x4f64(aval, 1.0, zero, 0, 0, 0);
    v4d calC = __builtin_amdgcn_mfma_f64_16x16x4f64(1.0, aval, zero, 0, 0, 0);
    int rIdx[4], cIdx[4];
    #pragma unroll
    for (int i = 0; i < 4; ++i) {
        rIdx[i] = (int)(calR[i] * 0.25);
        cIdx[i] = (int)(calC[i] * 0.25);
    }

    auto load_tile = [&](int s0, float* px, float* pa) {
        int ss = k_lo + s0 + kl;
        bool sv = ss < k_hi;
        #pragma unroll
        for (int i = 0; i < 8; ++i)
            px[i] = sv ? XF[(size_t)(r0 + rl + 8 * i) * NFREQ + O + ss] : 0.0f;
        #pragma unroll
        for (int j = 0; j < 8; ++j) {
            int d = d0 + rl + 8 * j;
            pa[j] = (sv && d < S) ? A[(size_t)d * S + ss] : 0.0f;
        }
    };

    v4d acc00 = zero, acc01 = zero, acc10 = zero, acc11 = zero;
    float px[8], pa[8];
    load_tile(0, px, pa);
    int nsteps = (k_hi - k_lo + 31) / 32;   // 6 (half 0) or 5 (half 1)
    for (int st = 0; st < nsteps; ++st) {
        __syncthreads();
        #pragma unroll
        for (int i = 0; i < 8; ++i) sX[rl + 8 * i][kl] = px[i];
        #pragma unroll
        for (int j = 0; j < 8; ++j) sA[rl + 8 * j][kl] = pa[j];
        __syncthreads();
        if (st + 1 < nsteps) load_tile((st + 1) * 32, px, pa);
        #pragma unroll
        for (int t = 0; t < 8; ++t) {
            int k = 4 * t + kq;
            double a0 = (double)sX[wm + fm][k];
            double a1 = (double)sX[wm + 16 + fm][k];
            double b0 = (double)sA[wn + fm][k];
            double b1 = (double)sA[wn + 16 + fm][k];
            acc00 = __builtin_amdgcn_mfma_f64_16x16x4f64(a0, b0, acc00, 0, 0, 0);
            acc01 = __builtin_amdgcn_mfma_f64_16x16x4f64(a0, b1, acc01, 0, 0, 0);
            acc10 = __builtin_amdgcn_mfma_f64_16x16x4f64(a1, b0, acc10, 0, 0, 0);
            acc11 = __builtin_amdgcn_mfma_f64_16x16x4f64(a1, b1, acc11, 0, 0, 0);
        }
    }
    // layout-agnostic atomic accumulate via calibrated indices
    #pragma unroll
    for (int i = 0; i < 4; ++i) {
        int rowA = r0 + wm + rIdx[i];
        int rowB = rowA + 16;
        int dA = d0 + wn + cIdx[i];
        int dB = dA + 16;
        if (dA < S) {
            unsafeAtomicAdd(&Y[(size_t)rowA * NFREQ + O + dA], acc00[i]);
            unsafeAtomicAdd(&Y[(size_t)rowB * NFREQ + O + dA], acc10[i]);
        }
        if (dB < S) {
            unsafeAtomicAdd(&Y[(size_t)rowA * NFREQ + O + dB], acc01[i]);
            unsafeAtomicAdd(&Y[(size_t)rowB * NFREQ + O + dB], acc11[i]);
        }
    }
}

// ---------------- K4: weighted Gram partials via f64 MFMA, G = Yw Yw^T ----------------
// grid (32 batches, 8 dim-chunks); block 256 = 4 waves (2x2 quadrants of the 64x64 G).
__global__ __launch_bounds__(256) void k_dist(const double* __restrict__ Y,
                                              const float* __restrict__ fw,
                                              double* __restrict__ part) {
    __shared__ double sY[64][34];   // [row][k] f64
    int b = blockIdx.x;
    int chunk = blockIdx.y;
    int dlo = chunk * 128;
    int dhi = (chunk == 7) ? NFREQ : dlo + 128;
    int tid = threadIdx.x;
    int lane = tid & 63, w = tid >> 6;
    int wm = (w >> 1) * 32, wn = (w & 1) * 32;
    int fm = lane & 15, kq = lane >> 4;
    int kl = tid & 31, rl = tid >> 5;

    double f0 = (double)fw[0], f1 = (double)fw[1], f2 = (double)fw[2];
    double m = fmax(f0, fmax(f1, f2));
    double e0 = exp(f0 - m), e1 = exp(f1 - m), e2 = exp(f2 - m);
    double esum = e0 + e1 + e2;
    double sw0 = sqrt(e0 / esum), sw1 = sqrt(e1 / esum), sw2 = sqrt(e2 / esum);

    v4d zero = {0.0, 0.0, 0.0, 0.0};
    double aval = (double)fm;
    v4d calR = __builtin_amdgcn_mfma_f64_16x16x4f64(aval, 1.0, zero, 0, 0, 0);
    v4d calC = __builtin_amdgcn_mfma_f64_16x16x4f64(1.0, aval, zero, 0, 0, 0);
    int rIdx[4], cIdx[4];
    #pragma unroll
    for (int i = 0; i < 4; ++i) {
        rIdx[i] = (int)(calR[i] * 0.25);
        cIdx[i] = (int)(calC[i] * 0.25);
    }

    const double* Yb = Y + (size_t)b * Cn * NFREQ;
    auto load_tile = [&](int k0, double* py) {
        int d = dlo + k0 + kl;
        bool dv = d < dhi;
        double sw = dv ? ((d < S0c) ? sw0 : ((d < S0c + S1c) ? sw1 : sw2)) : 0.0;
        #pragma unroll
        for (int i = 0; i < 8; ++i)
            py[i] = dv ? Yb[(size_t)(rl + 8 * i) * NFREQ + d] * sw : 0.0;
    };

    v4d acc00 = zero, acc01 = zero, acc10 = zero, acc11 = zero;
    double py[8];
    load_tile(0, py);
    int dk = dhi - dlo;
    int nsteps = (dk + 31) / 32;
    for (int st = 0; st < nsteps; ++st) {
        __syncthreads();
        #pragma unroll
        for (int i = 0; i < 8; ++i) sY[rl + 8 * i][kl] = py[i];
        __syncthreads();
        if (st + 1 < nsteps) load_tile((st + 1) * 32, py);
        #pragma unroll
        for (int t = 0; t < 8; ++t) {
            int k = 4 * t + kq;
            double a0 = sY[wm + fm][k];
            double a1 = sY[wm + 16 + fm][k];
            double b0 = sY[wn + fm][k];
            double b1 = sY[wn + 16 + fm][k];
            acc00 = __builtin_amdgcn_mfma_f64_16x16x4f64(a0, b0, acc00, 0, 0, 0);
            acc01 = __builtin_amdgcn_mfma_f64_16x16x4f64(a0, b1, acc01, 0, 0, 0);
            acc10 = __builtin_amdgcn_mfma_f64_16x16x4f64(a1, b0, acc10, 0, 0, 0);
            acc11 = __builtin_amdgcn_mfma_f64_16x16x4f64(a1, b1, acc11, 0, 0, 0);
        }
    }
    double* pb = part + (((size_t)b * 8 + chunk) << 12);
    #pragma unroll
    for (int i = 0; i < 4; ++i) {
        int rowA = wm + rIdx[i], rowB = rowA + 16;
        int cA = wn + cIdx[i], cB = cA + 16;
        pb[rowA * 64 + cA] = acc00[i];
        pb[rowA * 64 + cB] = acc01[i];
        pb[rowB * 64 + cA] = acc10[i];
        pb[rowB * 64 + cB] = acc11[i];
    }
}

// ---------------- K5: sum Gram partials, dist = Gii+Gjj-2Gij, gumbel decision ----------------
// grid (32 batches, 16 row-groups); block 256 = 4 waves, one wave per matrix row.
__global__ __launch_bounds__(256) void k_decide(const double* __restrict__ part,
                                                const float* __restrict__ gum,
                                                float* __restrict__ out) {
    __shared__ double sQ[64];
    int b = blockIdx.x;
    int tid = threadIdx.x;
    const double* pb = part + (((size_t)b * 8) << 12);
    if (tid < 64) {
        double q = 0.0;
        #pragma unroll
        for (int c = 0; c < 8; ++c) q += pb[((size_t)c << 12) + tid * 65];
        sQ[tid] = q;
    }
    __syncthreads();
    int i = blockIdx.y * 4 + (tid >> 6);
    int j = tid & 63;
    double g = 0.0;
    #pragma unroll
    for (int c = 0; c < 8; ++c) g += pb[((size_t)c << 12) + i * 64 + j];
    double dist = fmax(sQ[i] + sQ[j] - 2.0 * g, 0.0);
    double e = (i == j) ? 0.0 : 1.0 / (dist + 1e-10);
    double emax = e;
    #pragma unroll
    for (int off = 32; off; off >>= 1)
        emax = fmax(emax, __shfl_xor(emax, off, 64));
    double p = (i == j) ? 0.99 : (e / emax) * 0.99;
    double l0 = log(p / (1.0 - p));
    double l1 = log((1.0 - p) / p);
    int idx = i * 64 + j;
    const float* gb = gum + (size_t)b * 8192;
    double y0 = l0 + (double)gb[2 * idx];
    double y1 = l1 + (double)gb[2 * idx + 1];
    out[(size_t)b * 4096 + idx] = (y0 >= y1) ? 1.0f : 0.0f;  // ST == one-hot exactly
}

// ---------------- launcher ----------------
extern "C" void kernel_launch(void* const* d_in, const int* in_sizes, int n_in,
                              void* d_out, int out_size, void* d_ws, size_t ws_size,
                              hipStream_t stream) {
    const float* X  = (const float*)d_in[0];
    const float* A0 = (const float*)d_in[1];
    const float* A1 = (const float*)d_in[2];
    const float* A2 = (const float*)d_in[3];
    const float* fw = (const float*)d_in[4];
    const float* gm = (const float*)d_in[5];
    float* out = (float*)d_out;

    char* ws = (char*)d_ws;
    double2* tw  = (double2*)(ws);                 // 2048*16 = 32,768 B
    float*   XF  = (float*)(ws + 32768);           // 8,396,800 B
    double*  Y   = (double*)(ws + 8429568);        // 16,793,600 B (ends 25,223,168)
    // part aliases XF (dead after gemm): 32*8*4096*8 = 8,388,608 B
    double*  part = (double*)(ws + 32768);

    k_prep<<<2048, 256, 0, stream>>>(tw, Y);
    k_fft<<<Bn * Cn / 2, 256, 0, stream>>>(X, tw, XF);
    k_gemm<<<dim3(32, 6, 6), 256, 0, stream>>>(XF, A0, A1, A2, Y);
    k_dist<<<dim3(Bn, 8), 256, 0, stream>>>(Y, fw, part);
    k_decide<<<dim3(Bn, 16), 256, 0, stream>>>(part, gm, out);
}

// Round 10
// 172.130 us; speedup vs baseline: 1.0577x; 1.0577x over previous
//
#include <hip/hip_runtime.h>
#include <math.h>

#define Bn 32
#define Cn 64
#define Ln 2048
#define NFREQ 1025
#define S0c 341
#define S1c 341
#define S2c 343

#define PI_D 3.14159265358979323846

typedef double v4d __attribute__((ext_vector_type(4)));

// padded LDS index: breaks power-of-2 stride bank conflicts
#define PADIX(i) ((i) + ((i) >> 4))

// ---------------- K1: twiddle table tw[t] = e^{-2 pi i t / 2048}, t<2048 ----------------
__global__ void k_twiddle(double2* __restrict__ tw) {
    int t = blockIdx.x * blockDim.x + threadIdx.x;
    if (t < 2048) {
        double ang = -2.0 * PI_D * (double)t / 2048.0;
        double s, c;
        sincos(ang, &s, &c);
        tw[t] = make_double2(c, s);
    }
}

// radix-4 digit reversal of a 10-bit index
__device__ __forceinline__ int rev4_10(unsigned x) {
    unsigned t = __brev(x) >> 22;                       // full 10-bit reversal
    return (int)(((t & 0x155u) << 1) | ((t >> 1) & 0x155u));  // un-reverse bit pairs
}

// ---------------- K2: packed-real rfft via 1024-pt radix-4 complex FFT + split ----------------
__global__ __launch_bounds__(256) void k_fft(const float* __restrict__ X,
                                             const double2* __restrict__ tw,
                                             float* __restrict__ XF) {
    __shared__ double re[1088];
    __shared__ double im[1088];
    int row = blockIdx.x;
    int tid = threadIdx.x;
    const float2* xr = (const float2*)(X + (size_t)row * Ln);
    for (int m = tid; m < 1024; m += 256) {
        float2 v = xr[m];
        re[PADIX(m)] = (double)v.x; im[PADIX(m)] = (double)v.y;  // z[m]=x[2m]+i x[2m+1]
    }
    __syncthreads();
    // 5 radix-4 DIF stages, 256 butterflies each (one per thread)
    #pragma unroll
    for (int s = 0; s < 5; ++s) {
        int log2Q = 8 - 2 * s;
        int Q = 1 << log2Q;
        int k = tid & (Q - 1);
        int g = tid >> log2Q;
        int base = (g << (log2Q + 2)) + k;
        int i0 = PADIX(base), i1 = PADIX(base + Q), i2 = PADIX(base + 2 * Q), i3 = PADIX(base + 3 * Q);
        double ar = re[i0], ai = im[i0];
        double br = re[i1], bi = im[i1];
        double cr = re[i2], ci = im[i2];
        double dr = re[i3], di = im[i3];
        int step = 2 << (2 * s);
        double2 w1 = tw[k * step];
        double2 w2 = tw[2 * k * step];
        double2 w3 = tw[3 * k * step];
        double t0r = ar + cr, t0i = ai + ci;
        double t1r = ar - cr, t1i = ai - ci;
        double t2r = br + dr, t2i = bi + di;
        double t3r = br - dr, t3i = bi - di;
        re[i0] = t0r + t2r; im[i0] = t0i + t2i;
        double u1r = t1r + t3i, u1i = t1i - t3r;
        re[i1] = u1r * w1.x - u1i * w1.y; im[i1] = u1r * w1.y + u1i * w1.x;
        double u2r = t0r - t2r, u2i = t0i - t2i;
        re[i2] = u2r * w2.x - u2i * w2.y; im[i2] = u2r * w2.y + u2i * w2.x;
        double u3r = t1r - t3i, u3i = t1i + t3r;
        re[i3] = u3r * w3.x - u3i * w3.y; im[i3] = u3r * w3.y + u3i * w3.x;
        __syncthreads();
    }
    // split: X[k] = E_k + e^{-2pi i k/2048} O_k from Z (positions radix-4-digit-reversed)
    float* out = XF + (size_t)row * NFREQ;
    for (int k = tid; k <= 1024; k += 256) {
        double Xr, Xi;
        if (k == 0)        { Xr = re[0] + im[0]; Xi = 0.0; }
        else if (k == 1024){ Xr = re[0] - im[0]; Xi = 0.0; }
        else {
            int rv  = PADIX(rev4_10((unsigned)k));
            int rv2 = PADIX(rev4_10((unsigned)(1024 - k)));
            double Zr = re[rv],  Zi = im[rv];
            double Wr = re[rv2], Wi = im[rv2];
            double Er = 0.5 * (Zr + Wr), Ei = 0.5 * (Zi - Wi);
            double Or = 0.5 * (Zi + Wi), Oi = -0.5 * (Zr - Wr);
            double2 t = tw[k];
            Xr = Er + t.x * Or - t.y * Oi;
            Xi = Ei + t.x * Oi + t.y * Or;
        }
        out[k] = (float)sqrt(Xr * Xr + Xi * Xi);
    }
}

// ---------------- K3: fused 3-band GEMM, in-block K-split, v_mfma_f64_16x16x4 ----------------
// grid (32, 6, 3) = 576 blocks; block 512 = 8 waves. Waves 0-3: quadrants x k[0,192);
// waves 4-7: same quadrants x k[192,S). Two-pass f64 merge through LDS (deterministic,
// no atomics). Row-major f32 LDS stride 34 (conflict-free, proven round 8).
__global__ __launch_bounds__(512) void k_gemm(const float* __restrict__ XF,
                                              const float* __restrict__ A0,
                                              const float* __restrict__ A1,
                                              const float* __restrict__ A2,
                                              double* __restrict__ Y) {
    const int Sarr[3] = {S0c, S1c, S2c};
    const int Oarr[3] = {0, S0c, S0c + S1c};
    int z = blockIdx.z;
    const float* A = (z == 0) ? A0 : ((z == 1) ? A1 : A2);
    int S = Sarr[z], O = Oarr[z];

    __shared__ float sX[2][64][34];        // [half][row][k]  (2-way free)
    __shared__ float sA[2][64][34];        // [half][col(d)][k]
    __shared__ double mbuf[4][16][32];     // merge buffer: quad x 16 rows x 32 cols (16 KB)
    int r0 = blockIdx.x * 64;
    int d0 = blockIdx.y * 64;
    int tid = threadIdx.x;
    int lane = tid & 63, w = tid >> 6;           // wave 0..7
    int hw = w >> 2, q = w & 3;                  // K-half, quadrant
    int wm = (q >> 1) * 32, wn = (q & 1) * 32;   // quadrant origin
    int fm = lane & 15, kq = lane >> 4;          // staged frag coords
    int hs = tid >> 8;                           // staging K-half (== hw)
    int t256 = tid & 255;
    int kl = t256 & 31, rl = t256 >> 5;          // staging coords within half

    const int KSPLIT = 192;                      // 6 steps of 32 (exact)
    int k_lo = hs ? KSPLIT : 0;
    int k_hi = hs ? S : KSPLIT;

    // ---- runtime layout calibration (proven round 7) ----
    v4d zero = {0.0, 0.0, 0.0, 0.0};
    double aval = (double)fm;
    v4d calR = __builtin_amdgcn_mfma_f64_16x16x4f64(aval, 1.0, zero, 0, 0, 0);
    v4d calC = __builtin_amdgcn_mfma_f64_16x16x4f64(1.0, aval, zero, 0, 0, 0);
    int rIdx[4], cIdx[4];
    #pragma unroll
    for (int i = 0; i < 4; ++i) {
        rIdx[i] = (int)(calR[i] * 0.25);
        cIdx[i] = (int)(calC[i] * 0.25);
    }

    auto load_tile = [&](int st, float* px, float* pa) {
        int ss = k_lo + st * 32 + kl;
        bool sv = ss < k_hi;
        #pragma unroll
        for (int i = 0; i < 8; ++i)
            px[i] = sv ? XF[(size_t)(r0 + rl + 8 * i) * NFREQ + O + ss] : 0.0f;
        #pragma unroll
        for (int j = 0; j < 8; ++j) {
            int d = d0 + rl + 8 * j;
            pa[j] = (sv && d < S) ? A[(size_t)d * S + ss] : 0.0f;
        }
    };

    v4d acc00 = zero, acc01 = zero, acc10 = zero, acc11 = zero;
    float px[8], pa[8];
    load_tile(0, px, pa);
    #pragma unroll 1
    for (int st = 0; st < 6; ++st) {
        __syncthreads();
        #pragma unroll
        for (int i = 0; i < 8; ++i) sX[hs][rl + 8 * i][kl] = px[i];
        #pragma unroll
        for (int j = 0; j < 8; ++j) sA[hs][rl + 8 * j][kl] = pa[j];
        __syncthreads();
        if (st + 1 < 6) load_tile(st + 1, px, pa);
        #pragma unroll
        for (int t = 0; t < 8; ++t) {
            int k = 4 * t + kq;
            double a0 = (double)sX[hw][wm + fm][k];
            double a1 = (double)sX[hw][wm + 16 + fm][k];
            double b0 = (double)sA[hw][wn + fm][k];
            double b1 = (double)sA[hw][wn + 16 + fm][k];
            acc00 = __builtin_amdgcn_mfma_f64_16x16x4f64(a0, b0, acc00, 0, 0, 0);
            acc01 = __builtin_amdgcn_mfma_f64_16x16x4f64(a0, b1, acc01, 0, 0, 0);
            acc10 = __builtin_amdgcn_mfma_f64_16x16x4f64(a1, b0, acc10, 0, 0, 0);
            acc11 = __builtin_amdgcn_mfma_f64_16x16x4f64(a1, b1, acc11, 0, 0, 0);
        }
    }
    // ---- two-pass merge (half-1 -> LDS, half-0 adds and stores) ----
    // Pass A: rows wm..wm+15 (acc00 | acc01)
    __syncthreads();
    if (hw == 1) {
        #pragma unroll
        for (int i = 0; i < 4; ++i) {
            mbuf[q][rIdx[i]][cIdx[i]]      = acc00[i];
            mbuf[q][rIdx[i]][cIdx[i] + 16] = acc01[i];
        }
    }
    __syncthreads();
    if (hw == 0) {
        #pragma unroll
        for (int i = 0; i < 4; ++i) {
            int row = r0 + wm + rIdx[i];
            int dA = d0 + wn + cIdx[i];
            int dB = dA + 16;
            if (dA < S) Y[(size_t)row * NFREQ + O + dA] = acc00[i] + mbuf[q][rIdx[i]][cIdx[i]];
            if (dB < S) Y[(size_t)row * NFREQ + O + dB] = acc01[i] + mbuf[q][rIdx[i]][cIdx[i] + 16];
        }
    }
    // Pass B: rows wm+16..wm+31 (acc10 | acc11)
    __syncthreads();
    if (hw == 1) {
        #pragma unroll
        for (int i = 0; i < 4; ++i) {
            mbuf[q][rIdx[i]][cIdx[i]]      = acc10[i];
            mbuf[q][rIdx[i]][cIdx[i] + 16] = acc11[i];
        }
    }
    __syncthreads();
    if (hw == 0) {
        #pragma unroll
        for (int i = 0; i < 4; ++i) {
            int row = r0 + wm + 16 + rIdx[i];
            int dA = d0 + wn + cIdx[i];
            int dB = dA + 16;
            if (dA < S) Y[(size_t)row * NFREQ + O + dA] = acc10[i] + mbuf[q][rIdx[i]][cIdx[i]];
            if (dB < S) Y[(size_t)row * NFREQ + O + dB] = acc11[i] + mbuf[q][rIdx[i]][cIdx[i] + 16];
        }
    }
}

// ---------------- K4: weighted Gram partials via f64 MFMA, G = Yw Yw^T ----------------
// grid (32 batches, 8 dim-chunks); block 256 = 4 waves (2x2 quadrants of the 64x64 G).
__global__ __launch_bounds__(256) void k_dist(const double* __restrict__ Y,
                                              const float* __restrict__ fw,
                                              double* __restrict__ part) {
    __shared__ double sY[64][34];   // [row][k] f64
    int b = blockIdx.x;
    int chunk = blockIdx.y;
    int dlo = chunk * 128;
    int dhi = (chunk == 7) ? NFREQ : dlo + 128;
    int tid = threadIdx.x;
    int lane = tid & 63, w = tid >> 6;
    int wm = (w >> 1) * 32, wn = (w & 1) * 32;
    int fm = lane & 15, kq = lane >> 4;
    int kl = tid & 31, rl = tid >> 5;

    double f0 = (double)fw[0], f1 = (double)fw[1], f2 = (double)fw[2];
    double m = fmax(f0, fmax(f1, f2));
    double e0 = exp(f0 - m), e1 = exp(f1 - m), e2 = exp(f2 - m);
    double esum = e0 + e1 + e2;
    double sw0 = sqrt(e0 / esum), sw1 = sqrt(e1 / esum), sw2 = sqrt(e2 / esum);

    v4d zero = {0.0, 0.0, 0.0, 0.0};
    double aval = (double)fm;
    v4d calR = __builtin_amdgcn_mfma_f64_16x16x4f64(aval, 1.0, zero, 0, 0, 0);
    v4d calC = __builtin_amdgcn_mfma_f64_16x16x4f64(1.0, aval, zero, 0, 0, 0);
    int rIdx[4], cIdx[4];
    #pragma unroll
    for (int i = 0; i < 4; ++i) {
        rIdx[i] = (int)(calR[i] * 0.25);
        cIdx[i] = (int)(calC[i] * 0.25);
    }

    const double* Yb = Y + (size_t)b * Cn * NFREQ;
    auto load_tile = [&](int k0, double* py) {
        int d = dlo + k0 + kl;
        bool dv = d < dhi;
        double sw = dv ? ((d < S0c) ? sw0 : ((d < S0c + S1c) ? sw1 : sw2)) : 0.0;
        #pragma unroll
        for (int i = 0; i < 8; ++i)
            py[i] = dv ? Yb[(size_t)(rl + 8 * i) * NFREQ + d] * sw : 0.0;
    };

    v4d acc00 = zero, acc01 = zero, acc10 = zero, acc11 = zero;
    double py[8];
    load_tile(0, py);
    int dk = dhi - dlo;
    int nsteps = (dk + 31) / 32;
    for (int st = 0; st < nsteps; ++st) {
        __syncthreads();
        #pragma unroll
        for (int i = 0; i < 8; ++i) sY[rl + 8 * i][kl] = py[i];
        __syncthreads();
        if (st + 1 < nsteps) load_tile((st + 1) * 32, py);
        #pragma unroll
        for (int t = 0; t < 8; ++t) {
            int k = 4 * t + kq;
            double a0 = sY[wm + fm][k];
            double a1 = sY[wm + 16 + fm][k];
            double b0 = sY[wn + fm][k];
            double b1 = sY[wn + 16 + fm][k];
            acc00 = __builtin_amdgcn_mfma_f64_16x16x4f64(a0, b0, acc00, 0, 0, 0);
            acc01 = __builtin_amdgcn_mfma_f64_16x16x4f64(a0, b1, acc01, 0, 0, 0);
            acc10 = __builtin_amdgcn_mfma_f64_16x16x4f64(a1, b0, acc10, 0, 0, 0);
            acc11 = __builtin_amdgcn_mfma_f64_16x16x4f64(a1, b1, acc11, 0, 0, 0);
        }
    }
    double* pb = part + (((size_t)b * 8 + chunk) << 12);
    #pragma unroll
    for (int i = 0; i < 4; ++i) {
        int rowA = wm + rIdx[i], rowB = rowA + 16;
        int cA = wn + cIdx[i], cB = cA + 16;
        pb[rowA * 64 + cA] = acc00[i];
        pb[rowA * 64 + cB] = acc01[i];
        pb[rowB * 64 + cA] = acc10[i];
        pb[rowB * 64 + cB] = acc11[i];
    }
}

// ---------------- K5: sum Gram partials, dist = Gii+Gjj-2Gij, gumbel decision ----------------
// grid (32 batches, 16 row-groups); block 256 = 4 waves, one wave per matrix row.
__global__ __launch_bounds__(256) void k_decide(const double* __restrict__ part,
                                                const float* __restrict__ gum,
                                                float* __restrict__ out) {
    __shared__ double sQ[64];
    int b = blockIdx.x;
    int tid = threadIdx.x;
    const double* pb = part + (((size_t)b * 8) << 12);
    if (tid < 64) {
        double q = 0.0;
        #pragma unroll
        for (int c = 0; c < 8; ++c) q += pb[((size_t)c << 12) + tid * 65];
        sQ[tid] = q;
    }
    __syncthreads();
    int i = blockIdx.y * 4 + (tid >> 6);
    int j = tid & 63;
    double g = 0.0;
    #pragma unroll
    for (int c = 0; c < 8; ++c) g += pb[((size_t)c << 12) + i * 64 + j];
    double dist = fmax(sQ[i] + sQ[j] - 2.0 * g, 0.0);
    double e = (i == j) ? 0.0 : 1.0 / (dist + 1e-10);
    double emax = e;
    #pragma unroll
    for (int off = 32; off; off >>= 1)
        emax = fmax(emax, __shfl_xor(emax, off, 64));
    double p = (i == j) ? 0.99 : (e / emax) * 0.99;
    double l0 = log(p / (1.0 - p));
    double l1 = log((1.0 - p) / p);
    int idx = i * 64 + j;
    const float* gb = gum + (size_t)b * 8192;
    double y0 = l0 + (double)gb[2 * idx];
    double y1 = l1 + (double)gb[2 * idx + 1];
    out[(size_t)b * 4096 + idx] = (y0 >= y1) ? 1.0f : 0.0f;  // ST == one-hot exactly
}

// ---------------- launcher ----------------
extern "C" void kernel_launch(void* const* d_in, const int* in_sizes, int n_in,
                              void* d_out, int out_size, void* d_ws, size_t ws_size,
                              hipStream_t stream) {
    const float* X  = (const float*)d_in[0];
    const float* A0 = (const float*)d_in[1];
    const float* A1 = (const float*)d_in[2];
    const float* A2 = (const float*)d_in[3];
    const float* fw = (const float*)d_in[4];
    const float* gm = (const float*)d_in[5];
    float* out = (float*)d_out;

    char* ws = (char*)d_ws;
    double2* tw  = (double2*)(ws);                 // 2048*16 = 32,768 B
    float*   XF  = (float*)(ws + 32768);           // 8,396,800 B
    double*  Y   = (double*)(ws + 8429568);        // 16,793,600 B (ends 25,223,168)
    // part aliases XF (dead after gemm): 32*8*4096*8 = 8,388,608 B
    double*  part = (double*)(ws + 32768);

    k_twiddle<<<8, 256, 0, stream>>>(tw);
    k_fft<<<Bn * Cn, 256, 0, stream>>>(X, tw, XF);
    k_gemm<<<dim3(32, 6, 3), 512, 0, stream>>>(XF, A0, A1, A2, Y);
    k_dist<<<dim3(Bn, 8), 256, 0, stream>>>(Y, fw, part);
    k_decide<<<dim3(Bn, 16), 256, 0, stream>>>(part, gm, out);
}

// Round 11
// 170.916 us; speedup vs baseline: 1.0652x; 1.0071x over previous
//
#include <hip/hip_runtime.h>
#include <math.h>

#define Bn 32
#define Cn 64
#define Ln 2048
#define NFREQ 1025
#define S0c 341
#define S1c 341
#define S2c 343

#define PI_D 3.14159265358979323846

typedef double v4d __attribute__((ext_vector_type(4)));

// padded LDS index: breaks power-of-2 stride bank conflicts
#define PADIX(i) ((i) + ((i) >> 4))

// ---------------- K1: twiddle table tw[t] = e^{-2 pi i t / 2048}, t<2048 ----------------
__global__ void k_twiddle(double2* __restrict__ tw) {
    int t = blockIdx.x * blockDim.x + threadIdx.x;
    if (t < 2048) {
        double ang = -2.0 * PI_D * (double)t / 2048.0;
        double s, c;
        sincos(ang, &s, &c);
        tw[t] = make_double2(c, s);
    }
}

// radix-4 digit reversal of a 10-bit index
__device__ __forceinline__ int rev4_10(unsigned x) {
    unsigned t = __brev(x) >> 22;                       // full 10-bit reversal
    return (int)(((t & 0x155u) << 1) | ((t >> 1) & 0x155u));  // un-reverse bit pairs
}

// ---------------- K2: packed-real rfft, radix-4, stage-0 fused into load ----------------
__global__ __launch_bounds__(256) void k_fft(const float* __restrict__ X,
                                             const double2* __restrict__ tw,
                                             float* __restrict__ XF) {
    __shared__ double re[1088];
    __shared__ double im[1088];
    int row = blockIdx.x;
    int tid = threadIdx.x;
    const float2* xr = (const float2*)(X + (size_t)row * Ln);
    // ---- stage 0 (Q=256) computed in registers from global loads ----
    {
        int k = tid;
        float2 v0 = xr[k];
        float2 v1 = xr[k + 256];
        float2 v2 = xr[k + 512];
        float2 v3 = xr[k + 768];
        double ar = (double)v0.x, ai = (double)v0.y;
        double br = (double)v1.x, bi = (double)v1.y;
        double cr = (double)v2.x, ci = (double)v2.y;
        double dr = (double)v3.x, di = (double)v3.y;
        double2 w1 = tw[2 * k];
        double2 w2 = tw[4 * k];
        double2 w3 = tw[6 * k];
        double t0r = ar + cr, t0i = ai + ci;
        double t1r = ar - cr, t1i = ai - ci;
        double t2r = br + dr, t2i = bi + di;
        double t3r = br - dr, t3i = bi - di;
        int i0 = PADIX(k), i1 = PADIX(k + 256), i2 = PADIX(k + 512), i3 = PADIX(k + 768);
        re[i0] = t0r + t2r; im[i0] = t0i + t2i;
        double u1r = t1r + t3i, u1i = t1i - t3r;
        re[i1] = u1r * w1.x - u1i * w1.y; im[i1] = u1r * w1.y + u1i * w1.x;
        double u2r = t0r - t2r, u2i = t0i - t2i;
        re[i2] = u2r * w2.x - u2i * w2.y; im[i2] = u2r * w2.y + u2i * w2.x;
        double u3r = t1r - t3i, u3i = t1i + t3r;
        re[i3] = u3r * w3.x - u3i * w3.y; im[i3] = u3r * w3.y + u3i * w3.x;
    }
    __syncthreads();
    // ---- stages 1..4 through LDS ----
    #pragma unroll
    for (int s = 1; s < 5; ++s) {
        int log2Q = 8 - 2 * s;
        int Q = 1 << log2Q;
        int k = tid & (Q - 1);
        int g = tid >> log2Q;
        int base = (g << (log2Q + 2)) + k;
        int i0 = PADIX(base), i1 = PADIX(base + Q), i2 = PADIX(base + 2 * Q), i3 = PADIX(base + 3 * Q);
        double ar = re[i0], ai = im[i0];
        double br = re[i1], bi = im[i1];
        double cr = re[i2], ci = im[i2];
        double dr = re[i3], di = im[i3];
        int step = 2 << (2 * s);
        double2 w1 = tw[k * step];
        double2 w2 = tw[2 * k * step];
        double2 w3 = tw[3 * k * step];
        double t0r = ar + cr, t0i = ai + ci;
        double t1r = ar - cr, t1i = ai - ci;
        double t2r = br + dr, t2i = bi + di;
        double t3r = br - dr, t3i = bi - di;
        re[i0] = t0r + t2r; im[i0] = t0i + t2i;
        double u1r = t1r + t3i, u1i = t1i - t3r;
        re[i1] = u1r * w1.x - u1i * w1.y; im[i1] = u1r * w1.y + u1i * w1.x;
        double u2r = t0r - t2r, u2i = t0i - t2i;
        re[i2] = u2r * w2.x - u2i * w2.y; im[i2] = u2r * w2.y + u2i * w2.x;
        double u3r = t1r - t3i, u3i = t1i + t3r;
        re[i3] = u3r * w3.x - u3i * w3.y; im[i3] = u3r * w3.y + u3i * w3.x;
        __syncthreads();
    }
    // split: X[k] = E_k + e^{-2pi i k/2048} O_k from Z (positions radix-4-digit-reversed)
    float* out = XF + (size_t)row * NFREQ;
    for (int k = tid; k <= 1024; k += 256) {
        double Xr, Xi;
        if (k == 0)        { Xr = re[0] + im[0]; Xi = 0.0; }
        else if (k == 1024){ Xr = re[0] - im[0]; Xi = 0.0; }
        else {
            int rv  = PADIX(rev4_10((unsigned)k));
            int rv2 = PADIX(rev4_10((unsigned)(1024 - k)));
            double Zr = re[rv],  Zi = im[rv];
            double Wr = re[rv2], Wi = im[rv2];
            double Er = 0.5 * (Zr + Wr), Ei = 0.5 * (Zi - Wi);
            double Or = 0.5 * (Zi + Wi), Oi = -0.5 * (Zr - Wr);
            double2 t = tw[k];
            Xr = Er + t.x * Or - t.y * Oi;
            Xi = Ei + t.x * Oi + t.y * Or;
        }
        out[k] = (float)sqrt(Xr * Xr + Xi * Xi);
    }
}

// ---------------- K3: fused 3-band GEMM, quadrant-split, v_mfma_f64_16x16x4 ----------------
// grid (32 row-tiles, 6 col-tiles, 3 bands x 4 quadrants) = 2304 blocks (~9/CU);
// block 256 = 4 waves, each wave one 16x16 output tile (single accumulator chain).
// Same per-element k-accumulation order as rounds 7-10 -> bitwise identical results.
__global__ __launch_bounds__(256) void k_gemm(const float* __restrict__ XF,
                                              const float* __restrict__ A0,
                                              const float* __restrict__ A1,
                                              const float* __restrict__ A2,
                                              double* __restrict__ Y) {
    const int Sarr[3] = {S0c, S1c, S2c};
    const int Oarr[3] = {0, S0c, S0c + S1c};
    int bz = blockIdx.z;
    int z = bz >> 2, q = bz & 3;
    const float* A = (z == 0) ? A0 : ((z == 1) ? A1 : A2);
    int S = Sarr[z], O = Oarr[z];
    int qm = q >> 1, qn = q & 1;

    __shared__ float sX[32][34];   // [row][k] (proven conflict-free shape, round 8)
    __shared__ float sA[32][34];   // [col(d)][k]
    int r0 = blockIdx.x * 64 + qm * 32;
    int d0 = blockIdx.y * 64 + qn * 32;
    int tid = threadIdx.x;
    int lane = tid & 63, w = tid >> 6;
    int lm = (w >> 1) * 16, ln = (w & 1) * 16;   // wave's 16x16 tile within the 32x32
    int fm = lane & 15, kq = lane >> 4;
    int kl = tid & 31, rl = tid >> 5;            // staging coords (rl 0..7)

    // ---- runtime layout calibration (proven round 7) ----
    v4d zero = {0.0, 0.0, 0.0, 0.0};
    double aval = (double)fm;
    v4d calR = __builtin_amdgcn_mfma_f64_16x16x4f64(aval, 1.0, zero, 0, 0, 0);
    v4d calC = __builtin_amdgcn_mfma_f64_16x16x4f64(1.0, aval, zero, 0, 0, 0);
    int rIdx[4], cIdx[4];
    #pragma unroll
    for (int i = 0; i < 4; ++i) {
        rIdx[i] = (int)(calR[i] * 0.25);
        cIdx[i] = (int)(calC[i] * 0.25);
    }

    auto load_tile = [&](int st, float* px, float* pa) {
        int ss = st * 32 + kl;
        bool sv = ss < S;
        #pragma unroll
        for (int i = 0; i < 4; ++i)
            px[i] = sv ? XF[(size_t)(r0 + rl + 8 * i) * NFREQ + O + ss] : 0.0f;
        #pragma unroll
        for (int j = 0; j < 4; ++j) {
            int d = d0 + rl + 8 * j;
            pa[j] = (sv && d < S) ? A[(size_t)d * S + ss] : 0.0f;
        }
    };

    v4d acc = zero;
    float px[4], pa[4];
    load_tile(0, px, pa);
    int nsteps = (S + 31) / 32;   // 11
    for (int st = 0; st < nsteps; ++st) {
        __syncthreads();
        #pragma unroll
        for (int i = 0; i < 4; ++i) sX[rl + 8 * i][kl] = px[i];
        #pragma unroll
        for (int j = 0; j < 4; ++j) sA[rl + 8 * j][kl] = pa[j];
        __syncthreads();
        if (st + 1 < nsteps) load_tile(st + 1, px, pa);
        #pragma unroll
        for (int t = 0; t < 8; ++t) {
            int k = 4 * t + kq;
            double a = (double)sX[lm + fm][k];
            double b = (double)sA[ln + fm][k];
            acc = __builtin_amdgcn_mfma_f64_16x16x4f64(a, b, acc, 0, 0, 0);
        }
    }
    #pragma unroll
    for (int i = 0; i < 4; ++i) {
        int row = r0 + lm + rIdx[i];
        int d = d0 + ln + cIdx[i];
        if (d < S) Y[(size_t)row * NFREQ + O + d] = acc[i];
    }
}

// ---------------- K4: weighted Gram partials, quadrant-split f64 MFMA ----------------
// grid (32 batches, 8 dim-chunks, 4 quadrants) = 1024 blocks (~4/CU); block 256 = 4
// waves, each one 16x16 tile of G. Same k-order as round 8 -> bitwise identical.
__global__ __launch_bounds__(256) void k_dist(const double* __restrict__ Y,
                                              const float* __restrict__ fw,
                                              double* __restrict__ part) {
    __shared__ double sYa[32][34];   // rows 32*qm..
    __shared__ double sYb[32][34];   // rows 32*qn..
    int b = blockIdx.x;
    int chunk = blockIdx.y;
    int q = blockIdx.z;
    int qm = q >> 1, qn = q & 1;
    int dlo = chunk * 128;
    int dhi = (chunk == 7) ? NFREQ : dlo + 128;
    int tid = threadIdx.x;
    int lane = tid & 63, w = tid >> 6;
    int lm = (w >> 1) * 16, ln = (w & 1) * 16;
    int fm = lane & 15, kq = lane >> 4;
    int kl = tid & 31, rl = tid >> 5;

    double f0 = (double)fw[0], f1 = (double)fw[1], f2 = (double)fw[2];
    double m = fmax(f0, fmax(f1, f2));
    double e0 = exp(f0 - m), e1 = exp(f1 - m), e2 = exp(f2 - m);
    double esum = e0 + e1 + e2;
    double sw0 = sqrt(e0 / esum), sw1 = sqrt(e1 / esum), sw2 = sqrt(e2 / esum);

    v4d zero = {0.0, 0.0, 0.0, 0.0};
    double aval = (double)fm;
    v4d calR = __builtin_amdgcn_mfma_f64_16x16x4f64(aval, 1.0, zero, 0, 0, 0);
    v4d calC = __builtin_amdgcn_mfma_f64_16x16x4f64(1.0, aval, zero, 0, 0, 0);
    int rIdx[4], cIdx[4];
    #pragma unroll
    for (int i = 0; i < 4; ++i) {
        rIdx[i] = (int)(calR[i] * 0.25);
        cIdx[i] = (int)(calC[i] * 0.25);
    }

    const double* Yb = Y + (size_t)b * Cn * NFREQ;
    auto load_tile = [&](int k0, double* pya, double* pyb) {
        int d = dlo + k0 + kl;
        bool dv = d < dhi;
        double sw = dv ? ((d < S0c) ? sw0 : ((d < S0c + S1c) ? sw1 : sw2)) : 0.0;
        #pragma unroll
        for (int i = 0; i < 4; ++i) {
            pya[i] = dv ? Yb[(size_t)(32 * qm + rl + 8 * i) * NFREQ + d] * sw : 0.0;
            pyb[i] = dv ? Yb[(size_t)(32 * qn + rl + 8 * i) * NFREQ + d] * sw : 0.0;
        }
    };

    v4d acc = zero;
    double pya[4], pyb[4];
    load_tile(0, pya, pyb);
    int nsteps = (dhi - dlo + 31) / 32;
    for (int st = 0; st < nsteps; ++st) {
        __syncthreads();
        #pragma unroll
        for (int i = 0; i < 4; ++i) {
            sYa[rl + 8 * i][kl] = pya[i];
            sYb[rl + 8 * i][kl] = pyb[i];
        }
        __syncthreads();
        if (st + 1 < nsteps) load_tile((st + 1) * 32, pya, pyb);
        #pragma unroll
        for (int t = 0; t < 8; ++t) {
            int k = 4 * t + kq;
            double a = sYa[lm + fm][k];
            double bb = sYb[ln + fm][k];
            acc = __builtin_amdgcn_mfma_f64_16x16x4f64(a, bb, acc, 0, 0, 0);
        }
    }
    double* pb = part + (((size_t)b * 8 + chunk) << 12);
    #pragma unroll
    for (int i = 0; i < 4; ++i) {
        int row = 32 * qm + lm + rIdx[i];
        int col = 32 * qn + ln + cIdx[i];
        pb[row * 64 + col] = acc[i];
    }
}

// ---------------- K5: sum Gram partials, dist = Gii+Gjj-2Gij, gumbel decision ----------------
// grid (32 batches, 16 row-groups); block 256 = 4 waves, one wave per matrix row.
__global__ __launch_bounds__(256) void k_decide(const double* __restrict__ part,
                                                const float* __restrict__ gum,
                                                float* __restrict__ out) {
    __shared__ double sQ[64];
    int b = blockIdx.x;
    int tid = threadIdx.x;
    const double* pb = part + (((size_t)b * 8) << 12);
    if (tid < 64) {
        double q = 0.0;
        #pragma unroll
        for (int c = 0; c < 8; ++c) q += pb[((size_t)c << 12) + tid * 65];
        sQ[tid] = q;
    }
    __syncthreads();
    int i = blockIdx.y * 4 + (tid >> 6);
    int j = tid & 63;
    double g = 0.0;
    #pragma unroll
    for (int c = 0; c < 8; ++c) g += pb[((size_t)c << 12) + i * 64 + j];
    double dist = fmax(sQ[i] + sQ[j] - 2.0 * g, 0.0);
    double e = (i == j) ? 0.0 : 1.0 / (dist + 1e-10);
    double emax = e;
    #pragma unroll
    for (int off = 32; off; off >>= 1)
        emax = fmax(emax, __shfl_xor(emax, off, 64));
    double p = (i == j) ? 0.99 : (e / emax) * 0.99;
    double l0 = log(p / (1.0 - p));
    double l1 = log((1.0 - p) / p);
    int idx = i * 64 + j;
    const float* gb = gum + (size_t)b * 8192;
    double y0 = l0 + (double)gb[2 * idx];
    double y1 = l1 + (double)gb[2 * idx + 1];
    out[(size_t)b * 4096 + idx] = (y0 >= y1) ? 1.0f : 0.0f;  // ST == one-hot exactly
}

// ---------------- launcher ----------------
extern "C" void kernel_launch(void* const* d_in, const int* in_sizes, int n_in,
                              void* d_out, int out_size, void* d_ws, size_t ws_size,
                              hipStream_t stream) {
    const float* X  = (const float*)d_in[0];
    const float* A0 = (const float*)d_in[1];
    const float* A1 = (const float*)d_in[2];
    const float* A2 = (const float*)d_in[3];
    const float* fw = (const float*)d_in[4];
    const float* gm = (const float*)d_in[5];
    float* out = (float*)d_out;

    char* ws = (char*)d_ws;
    double2* tw  = (double2*)(ws);                 // 2048*16 = 32,768 B
    float*   XF  = (float*)(ws + 32768);           // 8,396,800 B
    double*  Y   = (double*)(ws + 8429568);        // 16,793,600 B (ends 25,223,168)
    // part aliases XF (dead after gemm): 32*8*4096*8 = 8,388,608 B
    double*  part = (double*)(ws + 32768);

    k_twiddle<<<8, 256, 0, stream>>>(tw);
    k_fft<<<Bn * Cn, 256, 0, stream>>>(X, tw, XF);
    k_gemm<<<dim3(32, 6, 12), 256, 0, stream>>>(XF, A0, A1, A2, Y);
    k_dist<<<dim3(Bn, 8, 4), 256, 0, stream>>>(Y, fw, part);
    k_decide<<<dim3(Bn, 16), 256, 0, stream>>>(part, gm, out);
}

// Round 12
// 161.757 us; speedup vs baseline: 1.1256x; 1.0566x over previous
//
#include <hip/hip_runtime.h>
#include <math.h>

#define Bn 32
#define Cn 64
#define Ln 2048
#define NFREQ 1025
#define S0c 341
#define S1c 341
#define S2c 343

#define PI_D 3.14159265358979323846

typedef double v4d __attribute__((ext_vector_type(4)));

// padded LDS index: breaks power-of-2 stride bank conflicts
#define PADIX(i) ((i) + ((i) >> 4))

// ---------------- K1: twiddle table tw[t] = e^{-2 pi i t / 2048}, t<2048 ----------------
__global__ void k_twiddle(double2* __restrict__ tw) {
    int t = blockIdx.x * blockDim.x + threadIdx.x;
    if (t < 2048) {
        double ang = -2.0 * PI_D * (double)t / 2048.0;
        double s, c;
        sincos(ang, &s, &c);
        tw[t] = make_double2(c, s);
    }
}

// radix-4 digit reversal of a 10-bit index
__device__ __forceinline__ int rev4_10(unsigned x) {
    unsigned t = __brev(x) >> 22;                       // full 10-bit reversal
    return (int)(((t & 0x155u) << 1) | ((t >> 1) & 0x155u));  // un-reverse bit pairs
}

// ---------------- K2: packed-real rfft, radix-4, stage-0 fused into load ----------------
__global__ __launch_bounds__(256) void k_fft(const float* __restrict__ X,
                                             const double2* __restrict__ tw,
                                             float* __restrict__ XF) {
    __shared__ double re[1088];
    __shared__ double im[1088];
    int row = blockIdx.x;
    int tid = threadIdx.x;
    const float2* xr = (const float2*)(X + (size_t)row * Ln);
    // ---- stage 0 (Q=256) computed in registers from global loads ----
    {
        int k = tid;
        float2 v0 = xr[k];
        float2 v1 = xr[k + 256];
        float2 v2 = xr[k + 512];
        float2 v3 = xr[k + 768];
        double ar = (double)v0.x, ai = (double)v0.y;
        double br = (double)v1.x, bi = (double)v1.y;
        double cr = (double)v2.x, ci = (double)v2.y;
        double dr = (double)v3.x, di = (double)v3.y;
        double2 w1 = tw[2 * k];
        double2 w2 = tw[4 * k];
        double2 w3 = tw[6 * k];
        double t0r = ar + cr, t0i = ai + ci;
        double t1r = ar - cr, t1i = ai - ci;
        double t2r = br + dr, t2i = bi + di;
        double t3r = br - dr, t3i = bi - di;
        int i0 = PADIX(k), i1 = PADIX(k + 256), i2 = PADIX(k + 512), i3 = PADIX(k + 768);
        re[i0] = t0r + t2r; im[i0] = t0i + t2i;
        double u1r = t1r + t3i, u1i = t1i - t3r;
        re[i1] = u1r * w1.x - u1i * w1.y; im[i1] = u1r * w1.y + u1i * w1.x;
        double u2r = t0r - t2r, u2i = t0i - t2i;
        re[i2] = u2r * w2.x - u2i * w2.y; im[i2] = u2r * w2.y + u2i * w2.x;
        double u3r = t1r - t3i, u3i = t1i + t3r;
        re[i3] = u3r * w3.x - u3i * w3.y; im[i3] = u3r * w3.y + u3i * w3.x;
    }
    __syncthreads();
    // ---- stages 1..4 through LDS ----
    #pragma unroll
    for (int s = 1; s < 5; ++s) {
        int log2Q = 8 - 2 * s;
        int Q = 1 << log2Q;
        int k = tid & (Q - 1);
        int g = tid >> log2Q;
        int base = (g << (log2Q + 2)) + k;
        int i0 = PADIX(base), i1 = PADIX(base + Q), i2 = PADIX(base + 2 * Q), i3 = PADIX(base + 3 * Q);
        double ar = re[i0], ai = im[i0];
        double br = re[i1], bi = im[i1];
        double cr = re[i2], ci = im[i2];
        double dr = re[i3], di = im[i3];
        int step = 2 << (2 * s);
        double2 w1 = tw[k * step];
        double2 w2 = tw[2 * k * step];
        double2 w3 = tw[3 * k * step];
        double t0r = ar + cr, t0i = ai + ci;
        double t1r = ar - cr, t1i = ai - ci;
        double t2r = br + dr, t2i = bi + di;
        double t3r = br - dr, t3i = bi - di;
        re[i0] = t0r + t2r; im[i0] = t0i + t2i;
        double u1r = t1r + t3i, u1i = t1i - t3r;
        re[i1] = u1r * w1.x - u1i * w1.y; im[i1] = u1r * w1.y + u1i * w1.x;
        double u2r = t0r - t2r, u2i = t0i - t2i;
        re[i2] = u2r * w2.x - u2i * w2.y; im[i2] = u2r * w2.y + u2i * w2.x;
        double u3r = t1r - t3i, u3i = t1i + t3r;
        re[i3] = u3r * w3.x - u3i * w3.y; im[i3] = u3r * w3.y + u3i * w3.x;
        __syncthreads();
    }
    // split: X[k] = E_k + e^{-2pi i k/2048} O_k from Z (positions radix-4-digit-reversed)
    float* out = XF + (size_t)row * NFREQ;
    for (int k = tid; k <= 1024; k += 256) {
        double Xr, Xi;
        if (k == 0)        { Xr = re[0] + im[0]; Xi = 0.0; }
        else if (k == 1024){ Xr = re[0] - im[0]; Xi = 0.0; }
        else {
            int rv  = PADIX(rev4_10((unsigned)k));
            int rv2 = PADIX(rev4_10((unsigned)(1024 - k)));
            double Zr = re[rv],  Zi = im[rv];
            double Wr = re[rv2], Wi = im[rv2];
            double Er = 0.5 * (Zr + Wr), Ei = 0.5 * (Zi - Wi);
            double Or = 0.5 * (Zi + Wi), Oi = -0.5 * (Zr - Wr);
            double2 t = tw[k];
            Xr = Er + t.x * Or - t.y * Oi;
            Xi = Ei + t.x * Oi + t.y * Or;
        }
        out[k] = (float)sqrt(Xr * Xr + Xi * Xi);
    }
}

// ---------------- K3: fused 3-band GEMM, quadrant-split, BK=64, v_mfma_f64_16x16x4 ----------------
// grid (32 row-tiles, 6 col-tiles, 3 bands x 4 quadrants) = 2304 blocks (~9/CU);
// block 256 = 4 waves, each wave one 16x16 output tile. K padded to 384 = 6 steps of 64
// (zero contributions preserve values exactly). 12 barriers/block vs 22 at BK=32.
__global__ __launch_bounds__(256) void k_gemm(const float* __restrict__ XF,
                                              const float* __restrict__ A0,
                                              const float* __restrict__ A1,
                                              const float* __restrict__ A2,
                                              double* __restrict__ Y) {
    const int Sarr[3] = {S0c, S1c, S2c};
    const int Oarr[3] = {0, S0c, S0c + S1c};
    int bz = blockIdx.z;
    int z = bz >> 2, q = bz & 3;
    const float* A = (z == 0) ? A0 : ((z == 1) ? A1 : A2);
    int S = Sarr[z], O = Oarr[z];
    int qm = q >> 1, qn = q & 1;

    __shared__ float sX[32][66];   // [row][k] stride 66: writes/reads 2-way (free)
    __shared__ float sA[32][66];   // [col(d)][k]
    int r0 = blockIdx.x * 64 + qm * 32;
    int d0 = blockIdx.y * 64 + qn * 32;
    int tid = threadIdx.x;
    int lane = tid & 63, w = tid >> 6;
    int lm = (w >> 1) * 16, ln = (w & 1) * 16;   // wave's 16x16 tile within the 32x32
    int fm = lane & 15, kq = lane >> 4;
    int kl = tid & 63, rl = tid >> 6;            // staging coords (kl 0..63, rl 0..3)

    // ---- runtime layout calibration (proven round 7) ----
    v4d zero = {0.0, 0.0, 0.0, 0.0};
    double aval = (double)fm;
    v4d calR = __builtin_amdgcn_mfma_f64_16x16x4f64(aval, 1.0, zero, 0, 0, 0);
    v4d calC = __builtin_amdgcn_mfma_f64_16x16x4f64(1.0, aval, zero, 0, 0, 0);
    int rIdx[4], cIdx[4];
    #pragma unroll
    for (int i = 0; i < 4; ++i) {
        rIdx[i] = (int)(calR[i] * 0.25);
        cIdx[i] = (int)(calC[i] * 0.25);
    }

    auto load_tile = [&](int st, float* px, float* pa) {
        int ss = st * 64 + kl;
        bool sv = ss < S;
        #pragma unroll
        for (int i = 0; i < 8; ++i)
            px[i] = sv ? XF[(size_t)(r0 + rl + 4 * i) * NFREQ + O + ss] : 0.0f;
        #pragma unroll
        for (int j = 0; j < 8; ++j) {
            int d = d0 + rl + 4 * j;
            pa[j] = (sv && d < S) ? A[(size_t)d * S + ss] : 0.0f;
        }
    };

    v4d acc = zero;
    float px[8], pa[8];
    load_tile(0, px, pa);
    const int nsteps = 6;   // 384 >= S for all bands
    for (int st = 0; st < nsteps; ++st) {
        __syncthreads();
        #pragma unroll
        for (int i = 0; i < 8; ++i) sX[rl + 4 * i][kl] = px[i];
        #pragma unroll
        for (int j = 0; j < 8; ++j) sA[rl + 4 * j][kl] = pa[j];
        __syncthreads();
        if (st + 1 < nsteps) load_tile(st + 1, px, pa);
        #pragma unroll
        for (int t = 0; t < 16; ++t) {
            int k = 4 * t + kq;
            double a = (double)sX[lm + fm][k];
            double b = (double)sA[ln + fm][k];
            acc = __builtin_amdgcn_mfma_f64_16x16x4f64(a, b, acc, 0, 0, 0);
        }
    }
    #pragma unroll
    for (int i = 0; i < 4; ++i) {
        int row = r0 + lm + rIdx[i];
        int d = d0 + ln + cIdx[i];
        if (d < S) Y[(size_t)row * NFREQ + O + d] = acc[i];
    }
}

// ---------------- K4: weighted Gram partials via f64 MFMA, G = Yw Yw^T (round-8 form) ----------------
// grid (32 batches, 8 dim-chunks); block 256 = 4 waves (2x2 quadrants of the 64x64 G).
__global__ __launch_bounds__(256) void k_dist(const double* __restrict__ Y,
                                              const float* __restrict__ fw,
                                              double* __restrict__ part) {
    __shared__ double sY[64][34];   // [row][k] f64
    int b = blockIdx.x;
    int chunk = blockIdx.y;
    int dlo = chunk * 128;
    int dhi = (chunk == 7) ? NFREQ : dlo + 128;
    int tid = threadIdx.x;
    int lane = tid & 63, w = tid >> 6;
    int wm = (w >> 1) * 32, wn = (w & 1) * 32;
    int fm = lane & 15, kq = lane >> 4;
    int kl = tid & 31, rl = tid >> 5;

    double f0 = (double)fw[0], f1 = (double)fw[1], f2 = (double)fw[2];
    double m = fmax(f0, fmax(f1, f2));
    double e0 = exp(f0 - m), e1 = exp(f1 - m), e2 = exp(f2 - m);
    double esum = e0 + e1 + e2;
    double sw0 = sqrt(e0 / esum), sw1 = sqrt(e1 / esum), sw2 = sqrt(e2 / esum);

    v4d zero = {0.0, 0.0, 0.0, 0.0};
    double aval = (double)fm;
    v4d calR = __builtin_amdgcn_mfma_f64_16x16x4f64(aval, 1.0, zero, 0, 0, 0);
    v4d calC = __builtin_amdgcn_mfma_f64_16x16x4f64(1.0, aval, zero, 0, 0, 0);
    int rIdx[4], cIdx[4];
    #pragma unroll
    for (int i = 0; i < 4; ++i) {
        rIdx[i] = (int)(calR[i] * 0.25);
        cIdx[i] = (int)(calC[i] * 0.25);
    }

    const double* Yb = Y + (size_t)b * Cn * NFREQ;
    auto load_tile = [&](int k0, double* py) {
        int d = dlo + k0 + kl;
        bool dv = d < dhi;
        double sw = dv ? ((d < S0c) ? sw0 : ((d < S0c + S1c) ? sw1 : sw2)) : 0.0;
        #pragma unroll
        for (int i = 0; i < 8; ++i)
            py[i] = dv ? Yb[(size_t)(rl + 8 * i) * NFREQ + d] * sw : 0.0;
    };

    v4d acc00 = zero, acc01 = zero, acc10 = zero, acc11 = zero;
    double py[8];
    load_tile(0, py);
    int nsteps = (dhi - dlo + 31) / 32;
    for (int st = 0; st < nsteps; ++st) {
        __syncthreads();
        #pragma unroll
        for (int i = 0; i < 8; ++i) sY[rl + 8 * i][kl] = py[i];
        __syncthreads();
        if (st + 1 < nsteps) load_tile((st + 1) * 32, py);
        #pragma unroll
        for (int t = 0; t < 8; ++t) {
            int k = 4 * t + kq;
            double a0 = sY[wm + fm][k];
            double a1 = sY[wm + 16 + fm][k];
            double b0 = sY[wn + fm][k];
            double b1 = sY[wn + 16 + fm][k];
            acc00 = __builtin_amdgcn_mfma_f64_16x16x4f64(a0, b0, acc00, 0, 0, 0);
            acc01 = __builtin_amdgcn_mfma_f64_16x16x4f64(a0, b1, acc01, 0, 0, 0);
            acc10 = __builtin_amdgcn_mfma_f64_16x16x4f64(a1, b0, acc10, 0, 0, 0);
            acc11 = __builtin_amdgcn_mfma_f64_16x16x4f64(a1, b1, acc11, 0, 0, 0);
        }
    }
    double* pb = part + (((size_t)b * 8 + chunk) << 12);
    #pragma unroll
    for (int i = 0; i < 4; ++i) {
        int rowA = wm + rIdx[i], rowB = rowA + 16;
        int cA = wn + cIdx[i], cB = cA + 16;
        pb[rowA * 64 + cA] = acc00[i];
        pb[rowA * 64 + cB] = acc01[i];
        pb[rowB * 64 + cA] = acc10[i];
        pb[rowB * 64 + cB] = acc11[i];
    }
}

// ---------------- K5: sum Gram partials, dist = Gii+Gjj-2Gij, gumbel decision ----------------
// grid (32 batches, 16 row-groups); block 256 = 4 waves, one wave per matrix row.
__global__ __launch_bounds__(256) void k_decide(const double* __restrict__ part,
                                                const float* __restrict__ gum,
                                                float* __restrict__ out) {
    __shared__ double sQ[64];
    int b = blockIdx.x;
    int tid = threadIdx.x;
    const double* pb = part + (((size_t)b * 8) << 12);
    if (tid < 64) {
        double q = 0.0;
        #pragma unroll
        for (int c = 0; c < 8; ++c) q += pb[((size_t)c << 12) + tid * 65];
        sQ[tid] = q;
    }
    __syncthreads();
    int i = blockIdx.y * 4 + (tid >> 6);
    int j = tid & 63;
    double g = 0.0;
    #pragma unroll
    for (int c = 0; c < 8; ++c) g += pb[((size_t)c << 12) + i * 64 + j];
    double dist = fmax(sQ[i] + sQ[j] - 2.0 * g, 0.0);
    double e = (i == j) ? 0.0 : 1.0 / (dist + 1e-10);
    double emax = e;
    #pragma unroll
    for (int off = 32; off; off >>= 1)
        emax = fmax(emax, __shfl_xor(emax, off, 64));
    double p = (i == j) ? 0.99 : (e / emax) * 0.99;
    double l0 = log(p / (1.0 - p));
    double l1 = log((1.0 - p) / p);
    int idx = i * 64 + j;
    const float* gb = gum + (size_t)b * 8192;
    double y0 = l0 + (double)gb[2 * idx];
    double y1 = l1 + (double)gb[2 * idx + 1];
    out[(size_t)b * 4096 + idx] = (y0 >= y1) ? 1.0f : 0.0f;  // ST == one-hot exactly
}

// ---------------- launcher ----------------
extern "C" void kernel_launch(void* const* d_in, const int* in_sizes, int n_in,
                              void* d_out, int out_size, void* d_ws, size_t ws_size,
                              hipStream_t stream) {
    const float* X  = (const float*)d_in[0];
    const float* A0 = (const float*)d_in[1];
    const float* A1 = (const float*)d_in[2];
    const float* A2 = (const float*)d_in[3];
    const float* fw = (const float*)d_in[4];
    const float* gm = (const float*)d_in[5];
    float* out = (float*)d_out;

    char* ws = (char*)d_ws;
    double2* tw  = (double2*)(ws);                 // 2048*16 = 32,768 B
    float*   XF  = (float*)(ws + 32768);           // 8,396,800 B
    double*  Y   = (double*)(ws + 8429568);        // 16,793,600 B (ends 25,223,168)
    // part aliases XF (dead after gemm): 32*8*4096*8 = 8,388,608 B
    double*  part = (double*)(ws + 32768);

    k_twiddle<<<8, 256, 0, stream>>>(tw);
    k_fft<<<Bn * Cn, 256, 0, stream>>>(X, tw, XF);
    k_gemm<<<dim3(32, 6, 12), 256, 0, stream>>>(XF, A0, A1, A2, Y);
    k_dist<<<dim3(Bn, 8), 256, 0, stream>>>(Y, fw, part);
    k_decide<<<dim3(Bn, 16), 256, 0, stream>>>(part, gm, out);
}